// Round 1
// baseline (279.058 us; speedup 1.0000x reference)
//
#include <hip/hip_runtime.h>
#include <stdint.h>

// ---------------------------------------------------------------------------
// GraphAttentionLayer fused pipeline, MI355X (gfx950)
// B=64 S=512 C=512 H=4 D=128.  All matmuls via split-bf16 (hi+lo) 3-term MFMA
// (~fp32 accuracy at bf16-MFMA rates).  Flash attention, never materializes
// the [H,B,S,S] score tensor.
// ---------------------------------------------------------------------------

typedef float  f32x4   __attribute__((ext_vector_type(4)));
typedef short  bf16x8  __attribute__((ext_vector_type(8)));
typedef unsigned short ushort8 __attribute__((ext_vector_type(8)));

#define GLD16(src, dst)                                                        \
  __builtin_amdgcn_global_load_lds(                                            \
      (const __attribute__((address_space(1))) void*)(src),                    \
      (__attribute__((address_space(3))) void*)(dst), 16, 0, 0)

__device__ __forceinline__ unsigned short f32_to_bf16(float x) {
  union { float f; unsigned int u; } v; v.f = x;
  unsigned int r = v.u + 0x7FFFu + ((v.u >> 16) & 1u);
  return (unsigned short)(r >> 16);
}
__device__ __forceinline__ float bf16_to_f32(unsigned short h) {
  union { float f; unsigned int u; } v; v.u = ((unsigned int)h) << 16;
  return v.f;
}
__device__ __forceinline__ f32x4 mfma16(bf16x8 a, bf16x8 b, f32x4 c) {
  return __builtin_amdgcn_mfma_f32_16x16x32_bf16(a, b, c, 0, 0, 0);
}

// ---------------------------------------------------------------------------
// Kernel 1: split h (fp32) -> h_hi, h_lo (bf16).  8 elems/thread.
// ---------------------------------------------------------------------------
__global__ __launch_bounds__(256) void cast_split_h(
    const float* __restrict__ src, unsigned short* __restrict__ dhi,
    unsigned short* __restrict__ dlo) {
  size_t i = ((size_t)blockIdx.x * 256 + threadIdx.x) * 8;
  f32x4 a = *(const f32x4*)(src + i);
  f32x4 b = *(const f32x4*)(src + i + 4);
  ushort8 hi, lo;
#pragma unroll
  for (int e = 0; e < 4; ++e) {
    unsigned short h0 = f32_to_bf16(a[e]);
    hi[e] = h0; lo[e] = f32_to_bf16(a[e] - bf16_to_f32(h0));
    unsigned short h1 = f32_to_bf16(b[e]);
    hi[4 + e] = h1; lo[4 + e] = f32_to_bf16(b[e] - bf16_to_f32(h1));
  }
  *(ushort8*)(dhi + i) = hi;
  *(ushort8*)(dlo + i) = lo;
}

// ---------------------------------------------------------------------------
// Kernel 2: W [H,C,D] fp32 -> Wt_hi/lo [H,D,C] bf16 (transposed per head).
// ---------------------------------------------------------------------------
__global__ __launch_bounds__(256) void cast_split_Wt(
    const float* __restrict__ W, unsigned short* __restrict__ whi,
    unsigned short* __restrict__ wlo) {
  int o = blockIdx.x * 256 + threadIdx.x;      // [0, 4*128*512)
  int hd = o >> 16;                             // head
  int rem = o & 65535;
  int d = rem >> 9;                             // [0,128)
  int c = rem & 511;                            // [0,512)
  float v = W[((size_t)(hd * 512 + c)) * 128 + d];
  unsigned short h0 = f32_to_bf16(v);
  whi[o] = h0;
  wlo[o] = f32_to_bf16(v - bf16_to_f32(h0));
}

// ---------------------------------------------------------------------------
// Kernel 3: projection GEMM  hp = h @ Wall + bias   ([32768x512]@[512x512])
// split-bf16 3-term.  128x128 tile, BK=32, 4 waves (2x2), 16x16x32 MFMA.
// LDS tiles row-major with XOR swizzle ((row>>1)&3)<<4 applied via
// pre-swizzled global source (linear global_load_lds dest).
// Outputs hp_hi/hp_lo (bf16 split of acc+bias), layout [32768][512].
// ---------------------------------------------------------------------------
__global__ __launch_bounds__(256, 2) void proj_gemm(
    const unsigned short* __restrict__ ahi, const unsigned short* __restrict__ alo,
    const unsigned short* __restrict__ whi, const unsigned short* __restrict__ wlo,
    const float* __restrict__ bias, unsigned short* __restrict__ hp_hi,
    unsigned short* __restrict__ hp_lo) {
  int bid = blockIdx.x;
  int swz = (bid & 7) * 128 + (bid >> 3);       // XCD-contiguous work chunks
  int nt = swz & 3, mt = swz >> 2;
  int m0 = mt * 128, n0 = nt * 128;             // n-tile == head nt

  __shared__ alignas(16) unsigned short Ah[128 * 32], Al[128 * 32];
  __shared__ alignas(16) unsigned short Bh[128 * 32], Bl[128 * 32];

  int tid = threadIdx.x, wv = tid >> 6, lane = tid & 63;
  int l15 = lane & 15, l4 = lane >> 4;
  int wr = wv >> 1, wc = wv & 1;

  f32x4 acc[4][4];
#pragma unroll
  for (int a = 0; a < 4; ++a)
#pragma unroll
    for (int b = 0; b < 4; ++b) acc[a][b] = (f32x4){0.f, 0.f, 0.f, 0.f};

  for (int ks = 0; ks < 16; ++ks) {
    int k0 = ks * 32;
    // stage: 32 x 1KB wave-instructions, tiles are [128 rows][32 k] (64B rows)
    for (int i = wv; i < 32; i += 4) {
      int grp = i >> 3, j = i & 7;
      int row = j * 16 + (lane >> 2);
      int off = (lane & 3) * 16;
      int sw = ((row >> 1) & 3) << 4;
      const unsigned short* sb;
      unsigned short* db;
      size_t srcoff;
      if (grp == 0)      { sb = ahi; db = Ah; srcoff = ((size_t)(m0 + row) * 512 + k0) * 2; }
      else if (grp == 1) { sb = alo; db = Al; srcoff = ((size_t)(m0 + row) * 512 + k0) * 2; }
      else if (grp == 2) { sb = whi; db = Bh; srcoff = ((size_t)(nt * 128 + row) * 512 + k0) * 2; }
      else               { sb = wlo; db = Bl; srcoff = ((size_t)(nt * 128 + row) * 512 + k0) * 2; }
      GLD16((const char*)sb + srcoff + (off ^ sw), db + j * 512);
    }
    __syncthreads();

    bf16x8 fah[4], fal[4], fbh[4], fbl[4];
#pragma unroll
    for (int f = 0; f < 4; ++f) {
      int mr = wr * 64 + f * 16 + l15;
      int aadr = mr * 64 + ((16 * l4) ^ (((mr >> 1) & 3) << 4));
      fah[f] = *(const bf16x8*)((const char*)Ah + aadr);
      fal[f] = *(const bf16x8*)((const char*)Al + aadr);
      int nr = wc * 64 + f * 16 + l15;
      int badr = nr * 64 + ((16 * l4) ^ (((nr >> 1) & 3) << 4));
      fbh[f] = *(const bf16x8*)((const char*)Bh + badr);
      fbl[f] = *(const bf16x8*)((const char*)Bl + badr);
    }
#pragma unroll
    for (int a = 0; a < 4; ++a)
#pragma unroll
      for (int b = 0; b < 4; ++b) {
        acc[a][b] = mfma16(fah[a], fbh[b], acc[a][b]);
        acc[a][b] = mfma16(fah[a], fbl[b], acc[a][b]);
        acc[a][b] = mfma16(fal[a], fbh[b], acc[a][b]);
      }
    __syncthreads();
  }

  // epilogue: +bias, split to bf16 hi/lo
#pragma unroll
  for (int b = 0; b < 4; ++b) {
    int ng = n0 + wc * 64 + b * 16 + l15;
    float bv = bias[ng];
#pragma unroll
    for (int a = 0; a < 4; ++a) {
#pragma unroll
      for (int r = 0; r < 4; ++r) {
        size_t mg = (size_t)m0 + wr * 64 + a * 16 + 4 * l4 + r;
        float v = acc[a][b][r] + bv;
        unsigned short h0 = f32_to_bf16(v);
        hp_hi[mg * 512 + ng] = h0;
        hp_lo[mg * 512 + ng] = f32_to_bf16(v - bf16_to_f32(h0));
      }
    }
  }
}

// ---------------------------------------------------------------------------
// Kernel 4: per-batch transpose  hpT[b][c][s] = hp[b*512+s][c]  (hi and lo)
// 64x64 tiles via LDS with XOR swizzle.
// ---------------------------------------------------------------------------
__global__ __launch_bounds__(256) void transpose_hp(
    const unsigned short* __restrict__ hp_hi, const unsigned short* __restrict__ hp_lo,
    unsigned short* __restrict__ hpT_hi, unsigned short* __restrict__ hpT_lo) {
  int bid = blockIdx.x;
  int ct = bid & 7, st = (bid >> 3) & 7, bb = bid >> 6;
  int s0 = st * 64, c0 = ct * 64;
  __shared__ alignas(16) unsigned short tile[64 * 64];
  int tid = threadIdx.x;
  int i = tid >> 3, j8 = (tid & 7) * 8;

  for (int p = 0; p < 2; ++p) {
    const unsigned short* src = p ? hp_lo : hp_hi;
    unsigned short* dst = p ? hpT_lo : hpT_hi;
#pragma unroll
    for (int h2 = 0; h2 < 2; ++h2) {
      int i2 = i + h2 * 32;
      ushort8 v = *(const ushort8*)(src + ((size_t)(bb * 512 + s0 + i2)) * 512 + c0 + j8);
      *(ushort8*)((char*)tile + ((i2 * 128 + j8 * 2) ^ ((i2 & 7) << 4))) = v;
    }
    __syncthreads();
#pragma unroll
    for (int h2 = 0; h2 < 2; ++h2) {
      int i2 = i + h2 * 32;
      ushort8 o;
#pragma unroll
      for (int e = 0; e < 8; ++e) {
        int srow = j8 + e;
        o[e] = *(const unsigned short*)((const char*)tile +
                 ((srow * 128 + i2 * 2) ^ ((srow & 7) << 4)));
      }
      *(ushort8*)(dst + ((size_t)(bb * 512 + c0 + i2)) * 512 + s0 + j8) = o;
    }
    __syncthreads();
  }
}

// ---------------------------------------------------------------------------
// Kernel 5: flash attention per (b, head, q-tile of 128). 4 waves, kv-tile 32.
// Swapped QK^T (A=K, B=Q) so each lane's softmax row index = l&15.
// P via LDS round-trip (hi/lo).  V from hpT (k-contiguous rows).
// All LDS tiles XOR-swizzled; staged with pre-swizzled global sources.
// Writes fp32 attention output (pre-LN) to `out` = d_out.
// ---------------------------------------------------------------------------
__global__ __launch_bounds__(256, 2) void attn_kernel(
    const unsigned short* __restrict__ hp_hi, const unsigned short* __restrict__ hp_lo,
    const unsigned short* __restrict__ hpT_hi, const unsigned short* __restrict__ hpT_lo,
    const float* __restrict__ adj, float* __restrict__ out) {
  int bid = blockIdx.x;
  int swz = (bid & 7) * 128 + (bid >> 3);       // XCD-contiguous: q-tiles of one
  int qt = swz & 3;                             // (b,head) stay on one XCD/L2
  int hd = (swz >> 2) & 3;
  int bb = swz >> 4;
  int q0 = qt * 128;

  __shared__ alignas(16) unsigned short K_hi[32 * 128], K_lo[32 * 128];   // [kv][d]
  __shared__ alignas(16) unsigned short Vt_hi[128 * 32], Vt_lo[128 * 32]; // [d][kv]
  __shared__ alignas(16) unsigned short P_hi[128 * 32], P_lo[128 * 32];   // [q][kv]
  __shared__ float sc_lds[128];

  int tid = threadIdx.x, w = tid >> 6, lane = tid & 63;
  int l15 = lane & 15, l4 = lane >> 4;

  // Q fragments (B-operand: n=q at l&15, k=d contiguous), hi+lo, in registers
  bf16x8 qh[2][4], ql[2][4];
#pragma unroll
  for (int nf = 0; nf < 2; ++nf) {
    size_t qrow = (size_t)bb * 512 + q0 + w * 32 + nf * 16 + l15;
#pragma unroll
    for (int ds = 0; ds < 4; ++ds) {
      size_t off = qrow * 512 + hd * 128 + ds * 32 + 8 * l4;
      qh[nf][ds] = *(const bf16x8*)(hp_hi + off);
      ql[nf][ds] = *(const bf16x8*)(hp_lo + off);
    }
  }

  f32x4 o[2][8];
#pragma unroll
  for (int qf = 0; qf < 2; ++qf)
#pragma unroll
    for (int vf = 0; vf < 8; ++vf) o[qf][vf] = (f32x4){0.f, 0.f, 0.f, 0.f};
  float m_run[2] = {-1e30f, -1e30f};
  float l_run[2] = {0.f, 0.f};

  for (int t = 0; t < 16; ++t) {
    int kv0 = t * 32;
    // ---- stage K [32][128] and Vt [128][32] (hi+lo), pre-swizzled sources
    for (int i = w; i < 32; i += 4) {
      int grp = i >> 3, j = i & 7;
      if (grp < 2) {                              // K rows are 256B
        int kv = j * 4 + (lane >> 4);
        int off = (lane & 15) * 16;
        int sw = (kv & 7) << 4;
        const unsigned short* sb = (grp == 0) ? hp_hi : hp_lo;
        unsigned short* db = ((grp == 0) ? K_hi : K_lo) + j * 512;
        const char* src = (const char*)sb +
            (((size_t)(bb * 512 + kv0 + kv)) * 512 + hd * 128) * 2 + (off ^ sw);
        GLD16(src, db);
      } else {                                    // Vt rows are 64B
        int d = j * 16 + (lane >> 2);
        int off = (lane & 3) * 16;
        int sw = ((d >> 1) & 3) << 4;
        const unsigned short* sb = (grp == 2) ? hpT_hi : hpT_lo;
        unsigned short* db = ((grp == 2) ? Vt_hi : Vt_lo) + j * 512;
        const char* src = (const char*)sb +
            (((size_t)(bb * 512 + hd * 128 + d)) * 512 + kv0) * 2 + (off ^ sw);
        GLD16(src, db);
      }
    }
    __syncthreads();

    // ---- scores = K @ Q^T (swapped): C[kv][q], 3-term split
    f32x4 sc[2][2];
#pragma unroll
    for (int mf = 0; mf < 2; ++mf)
#pragma unroll
      for (int nf = 0; nf < 2; ++nf) sc[mf][nf] = (f32x4){0.f, 0.f, 0.f, 0.f};
#pragma unroll
    for (int ds = 0; ds < 4; ++ds) {
      bf16x8 kh[2], kl[2];
#pragma unroll
      for (int mf = 0; mf < 2; ++mf) {
        int kvr = mf * 16 + l15;
        int adr = kvr * 256 + (((ds * 32 + 8 * l4) * 2) ^ ((kvr & 7) << 4));
        kh[mf] = *(const bf16x8*)((const char*)K_hi + adr);
        kl[mf] = *(const bf16x8*)((const char*)K_lo + adr);
      }
#pragma unroll
      for (int mf = 0; mf < 2; ++mf)
#pragma unroll
        for (int nf = 0; nf < 2; ++nf) {
          sc[mf][nf] = mfma16(kh[mf], qh[nf][ds], sc[mf][nf]);
          sc[mf][nf] = mfma16(kh[mf], ql[nf][ds], sc[mf][nf]);
          sc[mf][nf] = mfma16(kl[mf], qh[nf][ds], sc[mf][nf]);
        }
    }

    // ---- adj multiply + online softmax (row q = l&15 (+nf*16); kv in-lane)
#pragma unroll
    for (int nf = 0; nf < 2; ++nf) {
      int qg = q0 + w * 32 + nf * 16 + l15;      // q index in [0,512)
      float p[2][4];
      float tm = -1e30f;
#pragma unroll
      for (int mf = 0; mf < 2; ++mf) {
        int kvg = kv0 + mf * 16 + 4 * l4;
        f32x4 av = *(const f32x4*)(adj + (size_t)qg * 512 + kvg);
#pragma unroll
        for (int r = 0; r < 4; ++r) {
          float v = sc[mf][nf][r] * av[r];
          p[mf][r] = v;
          tm = fmaxf(tm, v);
        }
      }
      tm = fmaxf(tm, __shfl_xor(tm, 16));
      tm = fmaxf(tm, __shfl_xor(tm, 32));
      float mn = fmaxf(m_run[nf], tm);
      float scl = __expf(m_run[nf] - mn);
      m_run[nf] = mn;
      float ps = 0.f;
#pragma unroll
      for (int mf = 0; mf < 2; ++mf)
#pragma unroll
        for (int r = 0; r < 4; ++r) {
          p[mf][r] = __expf(p[mf][r] - mn);
          ps += p[mf][r];
        }
      ps += __shfl_xor(ps, 16);
      ps += __shfl_xor(ps, 32);
      l_run[nf] = l_run[nf] * scl + ps;
      sc_lds[w * 32 + nf * 16 + l15] = scl;       // per-q rescale broadcast

      // write P (hi/lo) to LDS [q][kv], swizzled, packed 4xbf16 (b64)
      int qloc = w * 32 + nf * 16 + l15;
      int swp = ((qloc >> 1) & 3) << 4;
#pragma unroll
      for (int mf = 0; mf < 2; ++mf) {
        int base = qloc * 64 + (((mf * 32 + l4 * 8)) ^ swp);
        union { unsigned short s[4]; uint2 u; } ph_, pl_;
#pragma unroll
        for (int r = 0; r < 4; ++r) {
          unsigned short h0 = f32_to_bf16(p[mf][r]);
          ph_.s[r] = h0;
          pl_.s[r] = f32_to_bf16(p[mf][r] - bf16_to_f32(h0));
        }
        *(uint2*)((char*)P_hi + base) = ph_.u;
        *(uint2*)((char*)P_lo + base) = pl_.u;
      }
    }

    // ---- rescale O, then O += P @ V (3-term); all same-wave LDS (in-order)
#pragma unroll
    for (int qf = 0; qf < 2; ++qf) {
      f32x4 s4 = *(const f32x4*)(sc_lds + w * 32 + qf * 16 + 4 * l4);
#pragma unroll
      for (int vf = 0; vf < 8; ++vf)
#pragma unroll
        for (int r = 0; r < 4; ++r) o[qf][vf][r] *= s4[r];
    }
    bf16x8 ph[2], pl[2];
#pragma unroll
    for (int qf = 0; qf < 2; ++qf) {
      int qloc = w * 32 + qf * 16 + l15;
      int adr = qloc * 64 + ((16 * l4) ^ (((qloc >> 1) & 3) << 4));
      ph[qf] = *(const bf16x8*)((const char*)P_hi + adr);
      pl[qf] = *(const bf16x8*)((const char*)P_lo + adr);
    }
#pragma unroll
    for (int vf = 0; vf < 8; ++vf) {
      int d = vf * 16 + l15;
      int adr = d * 64 + ((16 * l4) ^ (((d >> 1) & 3) << 4));
      bf16x8 vh = *(const bf16x8*)((const char*)Vt_hi + adr);
      bf16x8 vl = *(const bf16x8*)((const char*)Vt_lo + adr);
#pragma unroll
      for (int qf = 0; qf < 2; ++qf) {
        o[qf][vf] = mfma16(ph[qf], vh, o[qf][vf]);
        o[qf][vf] = mfma16(ph[qf], vl, o[qf][vf]);
        o[qf][vf] = mfma16(pl[qf], vh, o[qf][vf]);
      }
    }
    __syncthreads();   // protect K/Vt from next tile's staging
  }

  // ---- epilogue: divide by row sums, write fp32
#pragma unroll
  for (int nf = 0; nf < 2; ++nf) sc_lds[w * 32 + nf * 16 + l15] = l_run[nf];
#pragma unroll
  for (int qf = 0; qf < 2; ++qf) {
    f32x4 lv = *(const f32x4*)(sc_lds + w * 32 + qf * 16 + 4 * l4);
    float rl[4];
#pragma unroll
    for (int r = 0; r < 4; ++r) rl[r] = 1.0f / lv[r];
#pragma unroll
    for (int vf = 0; vf < 8; ++vf)
#pragma unroll
      for (int r = 0; r < 4; ++r) {
        size_t mg = (size_t)bb * 512 + q0 + w * 32 + qf * 16 + 4 * l4 + r;
        out[mg * 512 + hd * 128 + vf * 16 + l15] = o[qf][vf][r] * rl[r];
      }
  }
}

// ---------------------------------------------------------------------------
// Kernel 6: LayerNorm (over C=512) + exact-erf GELU, in place on d_out.
// One wave per row.
// ---------------------------------------------------------------------------
__global__ __launch_bounds__(256) void ln_gelu_kernel(
    float* __restrict__ io, const float* __restrict__ gamma,
    const float* __restrict__ beta) {
  int w = threadIdx.x >> 6, lane = threadIdx.x & 63;
  size_t row = (size_t)blockIdx.x * 4 + w;
  float* p = io + row * 512;
  f32x4 x0 = *(const f32x4*)(p + lane * 8);
  f32x4 x1 = *(const f32x4*)(p + lane * 8 + 4);
  float s = x0[0] + x0[1] + x0[2] + x0[3] + x1[0] + x1[1] + x1[2] + x1[3];
#pragma unroll
  for (int off = 32; off >= 1; off >>= 1) s += __shfl_xor(s, off);
  float mu = s * (1.0f / 512.0f);
  float vs = 0.f;
#pragma unroll
  for (int e = 0; e < 4; ++e) {
    float d0 = x0[e] - mu; vs += d0 * d0;
    float d1 = x1[e] - mu; vs += d1 * d1;
  }
#pragma unroll
  for (int off = 32; off >= 1; off >>= 1) vs += __shfl_xor(vs, off);
  float rs = rsqrtf(vs * (1.0f / 512.0f) + 1e-5f);
  f32x4 g0 = *(const f32x4*)(gamma + lane * 8);
  f32x4 g1 = *(const f32x4*)(gamma + lane * 8 + 4);
  f32x4 b0 = *(const f32x4*)(beta + lane * 8);
  f32x4 b1 = *(const f32x4*)(beta + lane * 8 + 4);
  f32x4 y0, y1;
#pragma unroll
  for (int e = 0; e < 4; ++e) {
    float y = (x0[e] - mu) * rs * g0[e] + b0[e];
    y0[e] = 0.5f * y * (1.0f + erff(y * 0.70710678118654752f));
    float z = (x1[e] - mu) * rs * g1[e] + b1[e];
    y1[e] = 0.5f * z * (1.0f + erff(z * 0.70710678118654752f));
  }
  *(f32x4*)(p + lane * 8) = y0;
  *(f32x4*)(p + lane * 8 + 4) = y1;
}

// ---------------------------------------------------------------------------
// Host launcher.  Inputs: [0]=t [1]=h [2]=W [3]=b [4]=adj [5]=gamma [6]=beta
// Workspace (~129 MB):
//   [0          ) h_hi  (16.7M us)  -- later reused as hpT_hi
//   [16777216   ) h_lo              -- later reused as hpT_lo
//   [33554432   ) hp_hi
//   [50331648   ) hp_lo
//   [67108864   ) Wt_hi (262144 us)
//   [67371008   ) Wt_lo
// ---------------------------------------------------------------------------
extern "C" void kernel_launch(void* const* d_in, const int* in_sizes, int n_in,
                              void* d_out, int out_size, void* d_ws, size_t ws_size,
                              hipStream_t stream) {
  const float* h     = (const float*)d_in[1];
  const float* W     = (const float*)d_in[2];
  const float* bias  = (const float*)d_in[3];
  const float* adj   = (const float*)d_in[4];
  const float* gamma = (const float*)d_in[5];
  const float* beta  = (const float*)d_in[6];
  float* out = (float*)d_out;

  unsigned short* ws = (unsigned short*)d_ws;
  unsigned short* h_hi   = ws;
  unsigned short* h_lo   = ws + 16777216;
  unsigned short* hp_hi  = ws + 33554432;
  unsigned short* hp_lo  = ws + 50331648;
  unsigned short* Wt_hi  = ws + 67108864;
  unsigned short* Wt_lo  = ws + 67371008;
  unsigned short* hpT_hi = h_hi;   // reuse: h_hi/h_lo dead after proj_gemm
  unsigned short* hpT_lo = h_lo;

  cast_split_h<<<8192, 256, 0, stream>>>(h, h_hi, h_lo);
  cast_split_Wt<<<1024, 256, 0, stream>>>(W, Wt_hi, Wt_lo);
  proj_gemm<<<1024, 256, 0, stream>>>(h_hi, h_lo, Wt_hi, Wt_lo, bias, hp_hi, hp_lo);
  transpose_hp<<<4096, 256, 0, stream>>>(hp_hi, hp_lo, hpT_hi, hpT_lo);
  attn_kernel<<<1024, 256, 0, stream>>>(hp_hi, hp_lo, hpT_hi, hpT_lo, adj, out);
  ln_gelu_kernel<<<8192, 256, 0, stream>>>(out, gamma, beta);
}

// Round 2
// 270.032 us; speedup vs baseline: 1.0334x; 1.0334x over previous
//
#include <hip/hip_runtime.h>
#include <stdint.h>

// ---------------------------------------------------------------------------
// GraphAttentionLayer fused pipeline, MI355X (gfx950)
// B=64 S=512 C=512 H=4 D=128.  Split-bf16 (hi+lo) 3-term MFMA everywhere.
// Round 2: attn q-tile 64 (occupancy 2->3+ blocks/CU), defer-rescale,
// trunc-split P pack, bpermute instead of sc_lds, proj writes hpT via b64.
// ---------------------------------------------------------------------------

typedef float  f32x4   __attribute__((ext_vector_type(4)));
typedef short  bf16x8  __attribute__((ext_vector_type(8)));
typedef unsigned short ushort8 __attribute__((ext_vector_type(8)));

#define GLD16(src, dst)                                                        \
  __builtin_amdgcn_global_load_lds(                                            \
      (const __attribute__((address_space(1))) void*)(src),                    \
      (__attribute__((address_space(3))) void*)(dst), 16, 0, 0)

__device__ __forceinline__ unsigned short f32_to_bf16(float x) {
  union { float f; unsigned int u; } v; v.f = x;
  unsigned int r = v.u + 0x7FFFu + ((v.u >> 16) & 1u);
  return (unsigned short)(r >> 16);
}
__device__ __forceinline__ float bf16_to_f32(unsigned short h) {
  union { float f; unsigned int u; } v; v.u = ((unsigned int)h) << 16;
  return v.f;
}
__device__ __forceinline__ f32x4 mfma16(bf16x8 a, bf16x8 b, f32x4 c) {
  return __builtin_amdgcn_mfma_f32_16x16x32_bf16(a, b, c, 0, 0, 0);
}
__device__ __forceinline__ float bperm_f(int srcLane, float v) {
  return __int_as_float(__builtin_amdgcn_ds_bpermute(srcLane << 2, __float_as_int(v)));
}

// ---------------------------------------------------------------------------
// Kernel 1: split h (fp32) -> h_hi, h_lo (bf16).  8 elems/thread.
// ---------------------------------------------------------------------------
__global__ __launch_bounds__(256) void cast_split_h(
    const float* __restrict__ src, unsigned short* __restrict__ dhi,
    unsigned short* __restrict__ dlo) {
  size_t i = ((size_t)blockIdx.x * 256 + threadIdx.x) * 8;
  f32x4 a = *(const f32x4*)(src + i);
  f32x4 b = *(const f32x4*)(src + i + 4);
  ushort8 hi, lo;
#pragma unroll
  for (int e = 0; e < 4; ++e) {
    unsigned short h0 = f32_to_bf16(a[e]);
    hi[e] = h0; lo[e] = f32_to_bf16(a[e] - bf16_to_f32(h0));
    unsigned short h1 = f32_to_bf16(b[e]);
    hi[4 + e] = h1; lo[4 + e] = f32_to_bf16(b[e] - bf16_to_f32(h1));
  }
  *(ushort8*)(dhi + i) = hi;
  *(ushort8*)(dlo + i) = lo;
}

// ---------------------------------------------------------------------------
// Kernel 2: W [H,C,D] fp32 -> Wt_hi/lo [H,D,C] bf16 (transposed per head).
// ---------------------------------------------------------------------------
__global__ __launch_bounds__(256) void cast_split_Wt(
    const float* __restrict__ W, unsigned short* __restrict__ whi,
    unsigned short* __restrict__ wlo) {
  int o = blockIdx.x * 256 + threadIdx.x;      // [0, 4*128*512)
  int hd = o >> 16;                             // head
  int rem = o & 65535;
  int d = rem >> 9;                             // [0,128)
  int c = rem & 511;                            // [0,512)
  float v = W[((size_t)(hd * 512 + c)) * 128 + d];
  unsigned short h0 = f32_to_bf16(v);
  whi[o] = h0;
  wlo[o] = f32_to_bf16(v - bf16_to_f32(h0));
}

// ---------------------------------------------------------------------------
// Kernel 3: projection GEMM  hp = h @ Wall + bias   ([32768x512]@[512x512])
// split-bf16 3-term.  128x128 tile, BK=32, 4 waves (2x2), 16x16x32 MFMA.
// Epilogue writes hpT [b][c][s] directly via packed uint2 (4 contiguous s).
// ---------------------------------------------------------------------------
__global__ __launch_bounds__(256, 2) void proj_gemm(
    const unsigned short* __restrict__ ahi, const unsigned short* __restrict__ alo,
    const unsigned short* __restrict__ whi, const unsigned short* __restrict__ wlo,
    const float* __restrict__ bias, unsigned short* __restrict__ hpT_hi,
    unsigned short* __restrict__ hpT_lo) {
  int bid = blockIdx.x;
  int swz = (bid & 7) * 128 + (bid >> 3);       // XCD-contiguous work chunks
  int nt = swz & 3, mt = swz >> 2;
  int m0 = mt * 128, n0 = nt * 128;             // n-tile == head nt

  __shared__ alignas(16) unsigned short Ah[128 * 32], Al[128 * 32];
  __shared__ alignas(16) unsigned short Bh[128 * 32], Bl[128 * 32];

  int tid = threadIdx.x, wv = tid >> 6, lane = tid & 63;
  int l15 = lane & 15, l4 = lane >> 4;
  int wr = wv >> 1, wc = wv & 1;

  f32x4 acc[4][4];
#pragma unroll
  for (int a = 0; a < 4; ++a)
#pragma unroll
    for (int b = 0; b < 4; ++b) acc[a][b] = (f32x4){0.f, 0.f, 0.f, 0.f};

  for (int ks = 0; ks < 16; ++ks) {
    int k0 = ks * 32;
    for (int i = wv; i < 32; i += 4) {
      int grp = i >> 3, j = i & 7;
      int row = j * 16 + (lane >> 2);
      int off = (lane & 3) * 16;
      int sw = ((row >> 1) & 3) << 4;
      const unsigned short* sb;
      unsigned short* db;
      size_t srcoff;
      if (grp == 0)      { sb = ahi; db = Ah; srcoff = ((size_t)(m0 + row) * 512 + k0) * 2; }
      else if (grp == 1) { sb = alo; db = Al; srcoff = ((size_t)(m0 + row) * 512 + k0) * 2; }
      else if (grp == 2) { sb = whi; db = Bh; srcoff = ((size_t)(nt * 128 + row) * 512 + k0) * 2; }
      else               { sb = wlo; db = Bl; srcoff = ((size_t)(nt * 128 + row) * 512 + k0) * 2; }
      GLD16((const char*)sb + srcoff + (off ^ sw), db + j * 512);
    }
    __syncthreads();

    bf16x8 fah[4], fal[4], fbh[4], fbl[4];
#pragma unroll
    for (int f = 0; f < 4; ++f) {
      int mr = wr * 64 + f * 16 + l15;
      int aadr = mr * 64 + ((16 * l4) ^ (((mr >> 1) & 3) << 4));
      fah[f] = *(const bf16x8*)((const char*)Ah + aadr);
      fal[f] = *(const bf16x8*)((const char*)Al + aadr);
      int nr = wc * 64 + f * 16 + l15;
      int badr = nr * 64 + ((16 * l4) ^ (((nr >> 1) & 3) << 4));
      fbh[f] = *(const bf16x8*)((const char*)Bh + badr);
      fbl[f] = *(const bf16x8*)((const char*)Bl + badr);
    }
#pragma unroll
    for (int a = 0; a < 4; ++a)
#pragma unroll
      for (int b = 0; b < 4; ++b) {
        acc[a][b] = mfma16(fah[a], fbh[b], acc[a][b]);
        acc[a][b] = mfma16(fah[a], fbl[b], acc[a][b]);
        acc[a][b] = mfma16(fal[a], fbh[b], acc[a][b]);
      }
    __syncthreads();
  }

  // epilogue: +bias, RNE split, write hpT[b][c][s] as 8B (4 contiguous s)
#pragma unroll
  for (int a = 0; a < 4; ++a) {
    int mg = m0 + wr * 64 + a * 16 + 4 * l4;
    int bbx = mg >> 9, ss = mg & 511;
#pragma unroll
    for (int b = 0; b < 4; ++b) {
      int ng = n0 + wc * 64 + b * 16 + l15;
      float bv = bias[ng];
      unsigned short h_[4], l_[4];
#pragma unroll
      for (int r = 0; r < 4; ++r) {
        float v = acc[a][b][r] + bv;
        unsigned short hh = f32_to_bf16(v);
        h_[r] = hh;
        l_[r] = f32_to_bf16(v - bf16_to_f32(hh));
      }
      size_t adr = ((size_t)bbx * 512 + ng) * 512 + ss;
      uint2 uh, ul;
      uh.x = (unsigned)h_[0] | ((unsigned)h_[1] << 16);
      uh.y = (unsigned)h_[2] | ((unsigned)h_[3] << 16);
      ul.x = (unsigned)l_[0] | ((unsigned)l_[1] << 16);
      ul.y = (unsigned)l_[2] | ((unsigned)l_[3] << 16);
      *(uint2*)(hpT_hi + adr) = uh;
      *(uint2*)(hpT_lo + adr) = ul;
    }
  }
}

// ---------------------------------------------------------------------------
// Kernel 4: generic per-batch transpose  dst[b][u][v] = src[b][v][u]
// (used as hpT [b][c][s] -> hp [b][s][c]).  64x64 tiles via LDS, XOR swizzle.
// ---------------------------------------------------------------------------
__global__ __launch_bounds__(256) void transpose_hp(
    const unsigned short* __restrict__ src_hi, const unsigned short* __restrict__ src_lo,
    unsigned short* __restrict__ dst_hi, unsigned short* __restrict__ dst_lo) {
  int bid = blockIdx.x;
  int ct = bid & 7, st = (bid >> 3) & 7, bb = bid >> 6;
  int s0 = st * 64, c0 = ct * 64;
  __shared__ alignas(16) unsigned short tile[64 * 64];
  int tid = threadIdx.x;
  int i = tid >> 3, j8 = (tid & 7) * 8;

  for (int p = 0; p < 2; ++p) {
    const unsigned short* src = p ? src_lo : src_hi;
    unsigned short* dst = p ? dst_lo : dst_hi;
#pragma unroll
    for (int h2 = 0; h2 < 2; ++h2) {
      int i2 = i + h2 * 32;
      ushort8 v = *(const ushort8*)(src + ((size_t)(bb * 512 + s0 + i2)) * 512 + c0 + j8);
      *(ushort8*)((char*)tile + ((i2 * 128 + j8 * 2) ^ ((i2 & 7) << 4))) = v;
    }
    __syncthreads();
#pragma unroll
    for (int h2 = 0; h2 < 2; ++h2) {
      int i2 = i + h2 * 32;
      ushort8 o;
#pragma unroll
      for (int e = 0; e < 8; ++e) {
        int srow = j8 + e;
        o[e] = *(const unsigned short*)((const char*)tile +
                 ((srow * 128 + i2 * 2) ^ ((srow & 7) << 4)));
      }
      *(ushort8*)(dst + ((size_t)(bb * 512 + c0 + i2)) * 512 + s0 + j8) = o;
    }
    __syncthreads();
  }
}

// ---------------------------------------------------------------------------
// Kernel 5: flash attention.  Block = (b, head, q-tile of 64), 4 waves of
// 16 q-rows each, kv-tile 32.  Swapped QK^T (A=K, B=Q) -> softmax row = l&15.
// Defer-rescale (THR=8), trunc-split P, bpermute for scl/l redistribution.
// LDS exactly 40 KiB.  Writes fp32 attention output (pre-LN) to out.
// ---------------------------------------------------------------------------
__global__ __launch_bounds__(256, 3) void attn_kernel(
    const unsigned short* __restrict__ hp_hi, const unsigned short* __restrict__ hp_lo,
    const unsigned short* __restrict__ hpT_hi, const unsigned short* __restrict__ hpT_lo,
    const float* __restrict__ adj, float* __restrict__ out) {
  int bid = blockIdx.x;
  int swz = (bid & 7) * 256 + (bid >> 3);       // 8 q-tiles of one (b,h) per XCD
  int qt = swz & 7;
  int hd = (swz >> 3) & 3;
  int bb = swz >> 5;
  int q0 = qt * 64;

  __shared__ alignas(16) unsigned short K_hi[32 * 128], K_lo[32 * 128];   // [kv][d]
  __shared__ alignas(16) unsigned short Vt_hi[128 * 32], Vt_lo[128 * 32]; // [d][kv]
  __shared__ alignas(16) unsigned short P_hi[64 * 32], P_lo[64 * 32];     // [q][kv]

  int tid = threadIdx.x, w = tid >> 6, lane = tid & 63;
  int l15 = lane & 15, l4 = lane >> 4;

  // Q fragments (B-operand: n=q at l&15, k=d contiguous), hi+lo, in registers
  bf16x8 qh[4], ql[4];
  {
    size_t qrow = (size_t)bb * 512 + q0 + w * 16 + l15;
    size_t base = qrow * 512 + hd * 128 + 8 * l4;
#pragma unroll
    for (int ds = 0; ds < 4; ++ds) {
      qh[ds] = *(const bf16x8*)(hp_hi + base + ds * 32);
      ql[ds] = *(const bf16x8*)(hp_lo + base + ds * 32);
    }
  }

  f32x4 o[8];
#pragma unroll
  for (int vf = 0; vf < 8; ++vf) o[vf] = (f32x4){0.f, 0.f, 0.f, 0.f};
  float m_run = -3.0e38f, l_run = 0.f;

  // staging: wave w owns one buffer
  const unsigned short* sb = (w == 0) ? hp_hi : (w == 1) ? hp_lo
                           : (w == 2) ? hpT_hi : hpT_lo;
  unsigned short* db = (w == 0) ? K_hi : (w == 1) ? K_lo
                     : (w == 2) ? Vt_hi : Vt_lo;
  const bool isK = (w < 2);

  for (int t = 0; t < 16; ++t) {
    int kv0 = t * 32;
    if (isK) {
      int kvl = lane >> 4, off = (lane & 15) * 16;
#pragma unroll
      for (int j = 0; j < 8; ++j) {
        int kvr = j * 4 + kvl;
        const char* src = (const char*)sb +
            (((size_t)(bb * 512 + kv0 + kvr)) * 512 + hd * 128) * 2 +
            (off ^ ((kvr & 7) << 4));
        GLD16(src, db + j * 512);
      }
    } else {
      int dl = lane >> 2, off = (lane & 3) * 16;
#pragma unroll
      for (int j = 0; j < 8; ++j) {
        int dr = j * 16 + dl;
        const char* src = (const char*)sb +
            (((size_t)(bb * 512 + hd * 128 + dr)) * 512 + kv0) * 2 +
            (off ^ (((dr >> 1) & 3) << 4));
        GLD16(src, db + j * 512);
      }
    }
    __syncthreads();

    // ---- scores = K @ Q^T (swapped): C[kv][q], 3-term split
    f32x4 sc0 = {0.f, 0.f, 0.f, 0.f}, sc1 = {0.f, 0.f, 0.f, 0.f};
#pragma unroll
    for (int ds = 0; ds < 4; ++ds) {
      int kb = (ds * 32 + 8 * l4) * 2;
      int r0 = l15, r1 = 16 + l15;
      int a0 = r0 * 256 + (kb ^ ((r0 & 7) << 4));
      int a1 = r1 * 256 + (kb ^ ((r1 & 7) << 4));
      bf16x8 kh0 = *(const bf16x8*)((const char*)K_hi + a0);
      bf16x8 kl0 = *(const bf16x8*)((const char*)K_lo + a0);
      bf16x8 kh1 = *(const bf16x8*)((const char*)K_hi + a1);
      bf16x8 kl1 = *(const bf16x8*)((const char*)K_lo + a1);
      sc0 = mfma16(kh0, qh[ds], sc0); sc1 = mfma16(kh1, qh[ds], sc1);
      sc0 = mfma16(kh0, ql[ds], sc0); sc1 = mfma16(kh1, ql[ds], sc1);
      sc0 = mfma16(kl0, qh[ds], sc0); sc1 = mfma16(kl1, qh[ds], sc1);
    }

    // ---- adj multiply + online softmax (row q = l&15; kv in-lane)
    int qg = q0 + w * 16 + l15;
    f32x4 av0 = *(const f32x4*)(adj + (size_t)qg * 512 + kv0 + 4 * l4);
    f32x4 av1 = *(const f32x4*)(adj + (size_t)qg * 512 + kv0 + 16 + 4 * l4);
    float p0[4], p1[4];
    float tm = -3.0e38f;
#pragma unroll
    for (int r = 0; r < 4; ++r) {
      p0[r] = sc0[r] * av0[r];
      p1[r] = sc1[r] * av1[r];
      tm = fmaxf(tm, fmaxf(p0[r], p1[r]));
    }
    tm = fmaxf(tm, __shfl_xor(tm, 16));
    tm = fmaxf(tm, __shfl_xor(tm, 32));
    if (__any(tm > m_run + 8.0f)) {           // T13 defer-rescale
      float mn = fmaxf(m_run, tm);
      float scl = __expf(m_run - mn);
      m_run = mn;
      l_run *= scl;
      f32x4 s4;
#pragma unroll
      for (int r = 0; r < 4; ++r) s4[r] = bperm_f(4 * l4 + r, scl);
#pragma unroll
      for (int vf = 0; vf < 8; ++vf)
#pragma unroll
        for (int r = 0; r < 4; ++r) o[vf][r] *= s4[r];
    }
    float ps = 0.f;
#pragma unroll
    for (int r = 0; r < 4; ++r) {
      p0[r] = __expf(p0[r] - m_run); ps += p0[r];
      p1[r] = __expf(p1[r] - m_run); ps += p1[r];
    }
    ps += __shfl_xor(ps, 16);
    ps += __shfl_xor(ps, 32);
    l_run += ps;

    // ---- pack P (trunc hi/lo) and write LDS [q][kv] (wave-private rows)
    int qloc = w * 16 + l15, swp = ((qloc >> 1) & 3) << 4;
    {
      unsigned ua0 = __float_as_uint(p0[0]), ua1 = __float_as_uint(p0[1]);
      unsigned ua2 = __float_as_uint(p0[2]), ua3 = __float_as_uint(p0[3]);
      uint2 uh, ul;
      uh.x = (ua0 >> 16) | (ua1 & 0xFFFF0000u);
      uh.y = (ua2 >> 16) | (ua3 & 0xFFFF0000u);
      float la0 = p0[0] - __uint_as_float(ua0 & 0xFFFF0000u);
      float la1 = p0[1] - __uint_as_float(ua1 & 0xFFFF0000u);
      float la2 = p0[2] - __uint_as_float(ua2 & 0xFFFF0000u);
      float la3 = p0[3] - __uint_as_float(ua3 & 0xFFFF0000u);
      ul.x = (__float_as_uint(la0) >> 16) | (__float_as_uint(la1) & 0xFFFF0000u);
      ul.y = (__float_as_uint(la2) >> 16) | (__float_as_uint(la3) & 0xFFFF0000u);
      int base = qloc * 64 + ((8 * l4) ^ swp);
      *(uint2*)((char*)P_hi + base) = uh;
      *(uint2*)((char*)P_lo + base) = ul;
    }
    {
      unsigned ua0 = __float_as_uint(p1[0]), ua1 = __float_as_uint(p1[1]);
      unsigned ua2 = __float_as_uint(p1[2]), ua3 = __float_as_uint(p1[3]);
      uint2 uh, ul;
      uh.x = (ua0 >> 16) | (ua1 & 0xFFFF0000u);
      uh.y = (ua2 >> 16) | (ua3 & 0xFFFF0000u);
      float la0 = p1[0] - __uint_as_float(ua0 & 0xFFFF0000u);
      float la1 = p1[1] - __uint_as_float(ua1 & 0xFFFF0000u);
      float la2 = p1[2] - __uint_as_float(ua2 & 0xFFFF0000u);
      float la3 = p1[3] - __uint_as_float(ua3 & 0xFFFF0000u);
      ul.x = (__float_as_uint(la0) >> 16) | (__float_as_uint(la1) & 0xFFFF0000u);
      ul.y = (__float_as_uint(la2) >> 16) | (__float_as_uint(la3) & 0xFFFF0000u);
      int base = qloc * 64 + ((32 + 8 * l4) ^ swp);
      *(uint2*)((char*)P_hi + base) = uh;
      *(uint2*)((char*)P_lo + base) = ul;
    }

    // ---- O += P @ V (3-term); same-wave LDS RAW is in-order
    {
      int pa = qloc * 64 + ((16 * l4) ^ swp);
      bf16x8 ph = *(const bf16x8*)((const char*)P_hi + pa);
      bf16x8 pl = *(const bf16x8*)((const char*)P_lo + pa);
#pragma unroll
      for (int vf = 0; vf < 8; ++vf) {
        int dd = vf * 16 + l15;
        int va = dd * 64 + ((16 * l4) ^ (((dd >> 1) & 3) << 4));
        bf16x8 vh = *(const bf16x8*)((const char*)Vt_hi + va);
        bf16x8 vl = *(const bf16x8*)((const char*)Vt_lo + va);
        o[vf] = mfma16(ph, vh, o[vf]);
        o[vf] = mfma16(ph, vl, o[vf]);
        o[vf] = mfma16(pl, vh, o[vf]);
      }
    }
    __syncthreads();   // protect K/Vt from next tile's staging
  }

  // ---- epilogue: divide by row sums (bpermute redistribution), write fp32
  float rinv = 1.0f / l_run;
  f32x4 r4;
#pragma unroll
  for (int r = 0; r < 4; ++r) r4[r] = bperm_f(4 * l4 + r, rinv);
#pragma unroll
  for (int vf = 0; vf < 8; ++vf)
#pragma unroll
    for (int r = 0; r < 4; ++r) {
      size_t mg = (size_t)bb * 512 + q0 + w * 16 + 4 * l4 + r;
      out[mg * 512 + hd * 128 + vf * 16 + l15] = o[vf][r] * r4[r];
    }
}

// ---------------------------------------------------------------------------
// Kernel 6: LayerNorm (over C=512) + exact-erf GELU, in place on d_out.
// ---------------------------------------------------------------------------
__global__ __launch_bounds__(256) void ln_gelu_kernel(
    float* __restrict__ io, const float* __restrict__ gamma,
    const float* __restrict__ beta) {
  int w = threadIdx.x >> 6, lane = threadIdx.x & 63;
  size_t row = (size_t)blockIdx.x * 4 + w;
  float* p = io + row * 512;
  f32x4 x0 = *(const f32x4*)(p + lane * 8);
  f32x4 x1 = *(const f32x4*)(p + lane * 8 + 4);
  float s = x0[0] + x0[1] + x0[2] + x0[3] + x1[0] + x1[1] + x1[2] + x1[3];
#pragma unroll
  for (int off = 32; off >= 1; off >>= 1) s += __shfl_xor(s, off);
  float mu = s * (1.0f / 512.0f);
  float vs = 0.f;
#pragma unroll
  for (int e = 0; e < 4; ++e) {
    float d0 = x0[e] - mu; vs += d0 * d0;
    float d1 = x1[e] - mu; vs += d1 * d1;
  }
#pragma unroll
  for (int off = 32; off >= 1; off >>= 1) vs += __shfl_xor(vs, off);
  float rs = rsqrtf(vs * (1.0f / 512.0f) + 1e-5f);
  f32x4 g0 = *(const f32x4*)(gamma + lane * 8);
  f32x4 g1 = *(const f32x4*)(gamma + lane * 8 + 4);
  f32x4 b0 = *(const f32x4*)(beta + lane * 8);
  f32x4 b1 = *(const f32x4*)(beta + lane * 8 + 4);
  f32x4 y0, y1;
#pragma unroll
  for (int e = 0; e < 4; ++e) {
    float y = (x0[e] - mu) * rs * g0[e] + b0[e];
    y0[e] = 0.5f * y * (1.0f + erff(y * 0.70710678118654752f));
    float z = (x1[e] - mu) * rs * g1[e] + b1[e];
    y1[e] = 0.5f * z * (1.0f + erff(z * 0.70710678118654752f));
  }
  *(f32x4*)(p + lane * 8) = y0;
  *(f32x4*)(p + lane * 8 + 4) = y1;
}

// ---------------------------------------------------------------------------
// Host launcher.  Inputs: [0]=t [1]=h [2]=W [3]=b [4]=adj [5]=gamma [6]=beta
// Workspace (~135 MB):
//   h_hi   = ws + 0          (16.7M u16)   -- reused as hp_hi after proj
//   h_lo   = ws + 16777216                 -- reused as hp_lo
//   hpT_hi = ws + 33554432   (written by proj_gemm)
//   hpT_lo = ws + 50331648
//   Wt_hi  = ws + 67108864   (262144 u16)
//   Wt_lo  = ws + 67371008
// ---------------------------------------------------------------------------
extern "C" void kernel_launch(void* const* d_in, const int* in_sizes, int n_in,
                              void* d_out, int out_size, void* d_ws, size_t ws_size,
                              hipStream_t stream) {
  const float* h     = (const float*)d_in[1];
  const float* W     = (const float*)d_in[2];
  const float* bias  = (const float*)d_in[3];
  const float* adj   = (const float*)d_in[4];
  const float* gamma = (const float*)d_in[5];
  const float* beta  = (const float*)d_in[6];
  float* out = (float*)d_out;

  unsigned short* ws = (unsigned short*)d_ws;
  unsigned short* h_hi   = ws;
  unsigned short* h_lo   = ws + 16777216;
  unsigned short* hpT_hi = ws + 33554432;
  unsigned short* hpT_lo = ws + 50331648;
  unsigned short* Wt_hi  = ws + 67108864;
  unsigned short* Wt_lo  = ws + 67371008;
  unsigned short* hp_hi  = h_hi;   // reuse: h_hi/h_lo dead after proj_gemm
  unsigned short* hp_lo  = h_lo;

  cast_split_h<<<8192, 256, 0, stream>>>(h, h_hi, h_lo);
  cast_split_Wt<<<1024, 256, 0, stream>>>(W, Wt_hi, Wt_lo);
  proj_gemm<<<1024, 256, 0, stream>>>(h_hi, h_lo, Wt_hi, Wt_lo, bias, hpT_hi, hpT_lo);
  transpose_hp<<<4096, 256, 0, stream>>>(hpT_hi, hpT_lo, hp_hi, hp_lo);
  attn_kernel<<<2048, 256, 0, stream>>>(hp_hi, hp_lo, hpT_hi, hpT_lo, adj, out);
  ln_gelu_kernel<<<8192, 256, 0, stream>>>(out, gamma, beta);
}